// Round 15
// baseline (468.550 us; speedup 1.0000x reference)
//
#include <hip/hip_runtime.h>
#include <hip/hip_cooperative_groups.h>
#include <math.h>

namespace cg = cooperative_groups;

#define NNODES 50000
#define NEDGES 800000
#define MPAD   50048   // NNODES rounded up to 128
#define NBLK   196     // ceil(NNODES/256)
#define PREP_XBLK 6256 // MPAD*128/4/256
#define PREP_WBLK 1024 // (131072+131072)/256
#define CNT_BLK   3125 // NEDGES/256

typedef __bf16 bf16_t;
typedef unsigned char u8;
typedef __attribute__((ext_vector_type(8))) __bf16 bf16x8;
typedef __attribute__((ext_vector_type(4))) float  floatx4;
typedef __attribute__((ext_vector_type(2))) float  floatx2;

__device__ __forceinline__ float bf_lo(unsigned u) { return __uint_as_float(u << 16); }
__device__ __forceinline__ float bf_hi(unsigned u) { return __uint_as_float(u & 0xffff0000u); }

__device__ __forceinline__ void gload_lds16(const bf16_t* g, bf16_t* l) {
    __builtin_amdgcn_global_load_lds(
        (const __attribute__((address_space(1))) unsigned int*)g,
        (__attribute__((address_space(3))) unsigned int*)l, 16, 0, 0);
}

struct W4 { const float* W[4]; };

// ---- fused prep (vectorized x cast + weight transposes) + count_deg w/ ordinal ----
__global__ void prep_count_kernel(const float* __restrict__ x, W4 w1, W4 w2,
                                  bf16_t* __restrict__ xb, bf16_t* __restrict__ wt1,
                                  bf16_t* __restrict__ wt2,
                                  const int* __restrict__ dst, int* __restrict__ deg,
                                  int* __restrict__ pack) {
    int b = blockIdx.x;
    if (b < PREP_XBLK) {
        int i = (b * 256 + threadIdx.x) * 4;
        if (i < MPAD * 128) {
            int row = i >> 7;
            bf16_t r[4];
            if (row < NNODES) {
                float4 v = *(const float4*)(x + i);
                r[0] = (bf16_t)v.x; r[1] = (bf16_t)v.y;
                r[2] = (bf16_t)v.z; r[3] = (bf16_t)v.w;
            } else { r[0] = r[1] = r[2] = r[3] = (bf16_t)0.f; }
            *(uint2*)(xb + i) = *(uint2*)r;
        }
    } else if (b < PREP_XBLK + PREP_WBLK) {
        int j = (b - PREP_XBLK) * 256 + threadIdx.x;   // 0..262143
        if (j < 131072) {
            int c = j >> 7, k = j & 127;
            wt1[j] = (bf16_t)w1.W[c >> 8][(size_t)k * 256 + (c & 255)];
        } else {
            int jj = j - 131072;
            int c = jj >> 8, k = jj & 255;
            wt2[jj] = (bf16_t)w2.W[c >> 7][(size_t)k * 128 + (c & 127)];
        }
    } else {
        int e = (b - PREP_XBLK - PREP_WBLK) * 256 + threadIdx.x;
        if (e < NEDGES) {
            int d = dst[e];
            int ord = atomicAdd(&deg[d], 1);   // per-destination ordinal (max deg << 2^15)
            pack[e] = (ord << 16) | d;         // dst < 50000 < 2^16
        }
    }
}

// ---- cooperative CSR: block sums -> scan partials -> row_ptr -> scatter ----
__global__ void csr_coop_kernel(const int* __restrict__ deg, int* __restrict__ psum,
                                int* __restrict__ row_ptr, const int* __restrict__ src,
                                const int* __restrict__ pack, int* __restrict__ esrc) {
    cg::grid_group grid = cg::this_grid();
    int t = threadIdx.x;
    int b = blockIdx.x;
    __shared__ int s[256];

    // phase A: per-block sum of deg
    int i = b * 256 + t;
    int v = (i < NNODES) ? deg[i] : 0;
    s[t] = v;
    __syncthreads();
    for (int off = 128; off; off >>= 1) {
        if (t < off) s[t] += s[t + off];
        __syncthreads();
    }
    if (t == 0) psum[b] = s[0];
    grid.sync();

    // phase B: block 0 exclusive-scans the 196 partials
    if (b == 0) {
        int pv = (t < NBLK) ? psum[t] : 0;
        s[t] = pv;
        __syncthreads();
        for (int off = 1; off < 256; off <<= 1) {
            int val = (t >= off) ? s[t - off] : 0;
            __syncthreads();
            s[t] += val;
            __syncthreads();
        }
        if (t < NBLK) psum[t] = s[t] - pv;   // exclusive
    }
    grid.sync();

    // phase C: per-block local scan -> row_ptr (exclusive prefix)
    s[t] = v;
    __syncthreads();
    for (int off = 1; off < 256; off <<= 1) {
        int val = (t >= off) ? s[t - off] : 0;
        __syncthreads();
        s[t] += val;
        __syncthreads();
    }
    if (i <= NNODES) row_ptr[i] = psum[b] + s[t] - v;
    grid.sync();

    // phase D: atomic-free scatter (slot = row_ptr[dst] + ordinal)
    for (int e = b * 256 + t; e < NEDGES; e += NBLK * 256) {
        int p = pack[e];
        int d = p & 0xFFFF;
        int ord = p >> 16;
        esrc[row_ptr[d] + ord] = src[e];
    }
}

// ---------------- bf16 MFMA GEMM: C_mat = (A @ W_mat + b_mat) * scale ----------------
// modes: 1 = bf16 contiguous (applies scale), 6 = fp8 contiguous,
//        2/3 = fp8 kv1 k/v half (row 512B, 4B groups), 4/5 = fp8 kv2 k/v half (row 256B)
struct GemmOut {
    const float* bias[4];
    void*        out[4];
    int          mode[4];
    float        scale[4];
};

template <int K, int NC>
__global__ __launch_bounds__(256) void gemm_mfma_kernel(const bf16_t* __restrict__ A,
                                                        const bf16_t* __restrict__ Wt,
                                                        GemmOut args) {
    __shared__ __align__(16) char smem[36864];
    bf16_t* As = (bf16_t*)smem;            // [128][64] swizzled = 16 KB
    bf16_t* Bs = (bf16_t*)(smem + 16384);  // [128][64] swizzled = 16 KB

    int t    = threadIdx.x;
    int lane = t & 63;
    int w    = t >> 6;
    int wm   = w >> 1, wn = w & 1;
    int tile_r = blockIdx.x * 128;
    int tile_c = blockIdx.y * 128;
    int mat = tile_c / NC;
    int tcl = tile_c % NC;

    int rl = lane >> 3;            // local row 0..7 within an 8-row group
    int sc = (lane & 7) ^ rl;      // which data chunk this lane must fetch

    floatx4 acc[4][4] = {};

    for (int kk = 0; kk < K; kk += 64) {
        #pragma unroll
        for (int j = 0; j < 4; j++) {
            int q = w * 4 + j;     // 8-row group 0..15
            const bf16_t* ga = &A [(size_t)(tile_r + q * 8 + rl) * K + kk + sc * 8];
            const bf16_t* gb = &Wt[(size_t)(tile_c + q * 8 + rl) * K + kk + sc * 8];
            gload_lds16(ga, As + q * 512);
            gload_lds16(gb, Bs + q * 512);
        }
        __syncthreads();
        #pragma unroll
        for (int kh = 0; kh < 64; kh += 32) {
            int sw = (((kh >> 3) + (lane >> 4)) ^ (lane & 7)) << 3;  // swizzled chunk offset
            bf16x8 af[4], bfr[4];
            #pragma unroll
            for (int mi = 0; mi < 4; mi++)
                af[mi] = *(const bf16x8*)&As[(wm * 64 + mi * 16 + (lane & 15)) * 64 + sw];
            #pragma unroll
            for (int ni = 0; ni < 4; ni++)
                bfr[ni] = *(const bf16x8*)&Bs[(wn * 64 + ni * 16 + (lane & 15)) * 64 + sw];
            #pragma unroll
            for (int mi = 0; mi < 4; mi++)
                #pragma unroll
                for (int ni = 0; ni < 4; ni++)
                    acc[mi][ni] = __builtin_amdgcn_mfma_f32_16x16x32_bf16(af[mi], bfr[ni], acc[mi][ni], 0, 0, 0);
        }
        __syncthreads();
    }

    // ---- LDS-staged coalesced epilogue ----
    const float* bias = args.bias[mat];
    void* op   = args.out[mat];
    int   mode = args.mode[mat];
    float scl  = args.scale[mat];
    float bv[4];
    #pragma unroll
    for (int ni = 0; ni < 4; ni++) bv[ni] = bias[tcl + wn * 64 + ni * 16 + (lane & 15)];

    if (mode == 1) {
        bf16_t (*Ct)[136] = (bf16_t(*)[136])smem;
        #pragma unroll
        for (int mi = 0; mi < 4; mi++)
            #pragma unroll
            for (int r = 0; r < 4; r++) {
                int row = wm * 64 + mi * 16 + (lane >> 4) * 4 + r;
                #pragma unroll
                for (int ni = 0; ni < 4; ni++) {
                    int col = wn * 64 + ni * 16 + (lane & 15);
                    Ct[row][col] = (bf16_t)((acc[mi][ni][r] + bv[ni]) * scl);
                }
            }
        __syncthreads();
        bf16_t* o = (bf16_t*)op;
        #pragma unroll
        for (int it = 0; it < 8; it++) {
            int idx = t + it * 256;
            int row = idx >> 4;
            int cg  = idx & 15;
            int gr = tile_r + row;
            if (gr < NNODES)
                *(int4*)(o + (size_t)gr * NC + tcl + cg * 8) = *(int4*)&Ct[row][cg * 8];
        }
    } else {
        u8 (*Ct8)[136] = (u8(*)[136])smem;
        #pragma unroll
        for (int mi = 0; mi < 4; mi++)
            #pragma unroll
            for (int r = 0; r < 4; r++) {
                int row = wm * 64 + mi * 16 + (lane >> 4) * 4 + r;
                #pragma unroll
                for (int ni = 0; ni < 4; ni++) {
                    int col = wn * 64 + ni * 16 + (lane & 15);
                    float val = acc[mi][ni][r] + bv[ni];
                    Ct8[row][col] = (u8)(__builtin_amdgcn_cvt_pk_fp8_f32(val, val, 0, false) & 0xff);
                }
            }
        __syncthreads();
        u8* o = (u8*)op;
        if (mode == 6) {
            // contiguous fp8
            #pragma unroll
            for (int it = 0; it < 16; it++) {
                int idx = t + it * 256;   // 0..4095
                int row = idx >> 5;
                int cg  = idx & 31;       // 4-byte col group
                int gr = tile_r + row;
                if (gr < NNODES) {
                    unsigned v4 = *(unsigned*)&Ct8[row][cg * 4];
                    *(unsigned*)(o + (size_t)gr * NC + tcl + cg * 4) = v4;
                }
            }
        } else if (mode <= 3) {
            bool isK = (mode == 2);
            #pragma unroll
            for (int it = 0; it < 16; it++) {
                int idx = t + it * 256;
                int row = idx >> 5;
                int cg  = idx & 31;
                int gr = tile_r + row;
                if (gr < NNODES) {
                    unsigned v4 = *(unsigned*)&Ct8[row][cg * 4];
                    size_t a = (size_t)gr * 512 + (size_t)((tcl >> 2) + cg) * 8 + (isK ? 0 : 4);
                    *(unsigned*)(o + a) = v4;
                }
            }
        } else {
            bool isK = (mode == 4);
            #pragma unroll
            for (int it = 0; it < 32; it++) {
                int idx = t + it * 256;
                int row = idx >> 6;
                int g   = idx & 63;
                int gr = tile_r + row;
                if (gr < NNODES) {
                    unsigned short v2 = *(unsigned short*)&Ct8[row][g * 2];
                    size_t a = (size_t)gr * 256 + (size_t)((tcl >> 1) + g) * 4 + (isK ? 0 : 2);
                    *(unsigned short*)(o + a) = v2;
                }
            }
        }
    }
}

// ---- attention layer 1 (heads=4, d=64): ONE WAVE PER NODE, group-of-4 ring ----
__device__ __forceinline__ void attn1_step(uint2 kvv, bool valid,
                                           float q0, float q1, float q2, float q3,
                                           float& l, float& a0, float& a1, float& a2, float& a3) {
    floatx2 ka = __builtin_amdgcn_cvt_pk_f32_fp8((int)kvv.x, false);
    floatx2 kb = __builtin_amdgcn_cvt_pk_f32_fp8((int)kvv.x, true);
    float p = q0 * ka.x + q1 * ka.y + q2 * kb.x + q3 * kb.y;
    p += __shfl_xor(p, 1, 64);
    p += __shfl_xor(p, 2, 64);
    p += __shfl_xor(p, 4, 64);
    p += __shfl_xor(p, 8, 64);
    p = valid ? p : -INFINITY;
    float pe = __expf(p);
    floatx2 va = __builtin_amdgcn_cvt_pk_f32_fp8((int)kvv.y, false);
    floatx2 vb = __builtin_amdgcn_cvt_pk_f32_fp8((int)kvv.y, true);
    l  += pe;
    a0 += pe * va.x;
    a1 += pe * va.y;
    a2 += pe * vb.x;
    a3 += pe * vb.y;
}

__global__ void attn1_kernel(const bf16_t* __restrict__ q, const u8* __restrict__ kv,
                             const u8* __restrict__ skipf8,
                             const int* __restrict__ row_ptr, const int* __restrict__ esrc,
                             bf16_t* __restrict__ hout) {
    int n = blockIdx.x * 4 + (threadIdx.x >> 6);
    int lane = threadIdx.x & 63;
    int off = lane * 4;
    size_t lb = (size_t)(lane * 8);

    int beg = row_ptr[n], end = row_ptr[n + 1];

    uint2 qu = *(const uint2*)(q + (size_t)n * 256 + off);
    float q0 = bf_lo(qu.x), q1 = bf_hi(qu.x), q2 = bf_lo(qu.y), q3 = bf_hi(qu.y);

    float l = 0.f, a0 = 0.f, a1 = 0.f, a2 = 0.f, a3 = 0.f;

    if (beg < end) {
        int last = end - 1;
        int s0 = esrc[beg];
        int s1 = esrc[min(beg + 1, last)];
        int s2 = esrc[min(beg + 2, last)];
        int s3 = esrc[min(beg + 3, last)];
        uint2 k0 = *(const uint2*)(kv + (size_t)s0 * 512 + lb);
        uint2 k1 = *(const uint2*)(kv + (size_t)s1 * 512 + lb);
        uint2 k2 = *(const uint2*)(kv + (size_t)s2 * 512 + lb);
        uint2 k3 = *(const uint2*)(kv + (size_t)s3 * 512 + lb);

        for (int i = beg; i < end; i += 4) {
            int b = i + 4;
            int ns0 = esrc[min(b,     last)];
            int ns1 = esrc[min(b + 1, last)];
            int ns2 = esrc[min(b + 2, last)];
            int ns3 = esrc[min(b + 3, last)];

            attn1_step(k0, true,        q0, q1, q2, q3, l, a0, a1, a2, a3);
            k0 = *(const uint2*)(kv + (size_t)ns0 * 512 + lb);
            attn1_step(k1, i + 1 < end, q0, q1, q2, q3, l, a0, a1, a2, a3);
            k1 = *(const uint2*)(kv + (size_t)ns1 * 512 + lb);
            attn1_step(k2, i + 2 < end, q0, q1, q2, q3, l, a0, a1, a2, a3);
            k2 = *(const uint2*)(kv + (size_t)ns2 * 512 + lb);
            attn1_step(k3, i + 3 < end, q0, q1, q2, q3, l, a0, a1, a2, a3);
            k3 = *(const uint2*)(kv + (size_t)ns3 * 512 + lb);
        }
    }

    float inv = (l > 0.f) ? 1.f / l : 0.f;
    size_t o = (size_t)n * 256 + off;
    unsigned sk = *(const unsigned*)(skipf8 + o);
    floatx2 s01 = __builtin_amdgcn_cvt_pk_f32_fp8((int)sk, false);
    floatx2 s23 = __builtin_amdgcn_cvt_pk_f32_fp8((int)sk, true);
    bf16_t r[4];
    r[0] = (bf16_t)fmaxf(s01.x + a0 * inv, 0.f);
    r[1] = (bf16_t)fmaxf(s01.y + a1 * inv, 0.f);
    r[2] = (bf16_t)fmaxf(s23.x + a2 * inv, 0.f);
    r[3] = (bf16_t)fmaxf(s23.y + a3 * inv, 0.f);
    *(uint2*)(hout + o) = *(uint2*)r;
}

// ---- attention layer 2 (heads=1, d=128): ONE WAVE PER NODE, 4 edges/iter ----
__device__ __forceinline__ void attn2_step(uint4 kvv, bool valid, const float* qf,
                                           float& l, float* a) {
    floatx2 k01 = __builtin_amdgcn_cvt_pk_f32_fp8((int)kvv.x, false);
    floatx2 k23 = __builtin_amdgcn_cvt_pk_f32_fp8((int)kvv.y, false);
    floatx2 k45 = __builtin_amdgcn_cvt_pk_f32_fp8((int)kvv.z, false);
    floatx2 k67 = __builtin_amdgcn_cvt_pk_f32_fp8((int)kvv.w, false);
    float p = qf[0] * k01.x + qf[1] * k01.y + qf[2] * k23.x + qf[3] * k23.y
            + qf[4] * k45.x + qf[5] * k45.y + qf[6] * k67.x + qf[7] * k67.y;
    p += __shfl_xor(p, 1, 64);
    p += __shfl_xor(p, 2, 64);
    p += __shfl_xor(p, 4, 64);
    p += __shfl_xor(p, 8, 64);
    p = valid ? p : -INFINITY;
    float pe = __expf(p);
    floatx2 v01 = __builtin_amdgcn_cvt_pk_f32_fp8((int)kvv.x, true);
    floatx2 v23 = __builtin_amdgcn_cvt_pk_f32_fp8((int)kvv.y, true);
    floatx2 v45 = __builtin_amdgcn_cvt_pk_f32_fp8((int)kvv.z, true);
    floatx2 v67 = __builtin_amdgcn_cvt_pk_f32_fp8((int)kvv.w, true);
    l    += pe;
    a[0] += pe * v01.x;
    a[1] += pe * v01.y;
    a[2] += pe * v23.x;
    a[3] += pe * v23.y;
    a[4] += pe * v45.x;
    a[5] += pe * v45.y;
    a[6] += pe * v67.x;
    a[7] += pe * v67.y;
}

__global__ void attn2_kernel(const bf16_t* __restrict__ q, const u8* __restrict__ kv,
                             const int* __restrict__ row_ptr, const int* __restrict__ esrc,
                             bf16_t* __restrict__ h2) {
    int n = blockIdx.x * 4 + (threadIdx.x >> 6);
    int lane = threadIdx.x & 63;
    int quad = lane >> 4;
    int sub  = lane & 15;
    int d0 = sub * 8;
    size_t lb = (size_t)(sub * 16);

    int beg = row_ptr[n], end = row_ptr[n + 1];

    uint4 qu = *(const uint4*)(q + (size_t)n * 128 + d0);
    float qf[8] = {bf_lo(qu.x), bf_hi(qu.x), bf_lo(qu.y), bf_hi(qu.y),
                   bf_lo(qu.z), bf_hi(qu.z), bf_lo(qu.w), bf_hi(qu.w)};

    float l = 0.f, a[8] = {};

    if (beg < end) {
        int last = end - 1;
        int s0 = esrc[min(beg + quad,     last)];
        int s1 = esrc[min(beg + 4 + quad, last)];
        uint4 k0 = *(const uint4*)(kv + (size_t)s0 * 256 + lb);
        uint4 k1 = *(const uint4*)(kv + (size_t)s1 * 256 + lb);

        for (int i = beg; i < end; i += 4) {
            int ns = esrc[min(i + 8 + quad, last)];
            attn2_step(k0, i + quad < end, qf, l, a);
            k0 = k1;
            k1 = *(const uint4*)(kv + (size_t)ns * 256 + lb);
        }
    }

    l += __shfl_xor(l, 16, 64);
    l += __shfl_xor(l, 32, 64);
    #pragma unroll
    for (int j = 0; j < 8; j++) {
        a[j] += __shfl_xor(a[j], 16, 64);
        a[j] += __shfl_xor(a[j], 32, 64);
    }
    float inv = (l > 0.f) ? 1.f / l : 0.f;
    if (quad == 0) {
        size_t o = (size_t)n * 128 + d0;
        uint4 cur = *(const uint4*)(h2 + o);
        float cf[8] = {bf_lo(cur.x), bf_hi(cur.x), bf_lo(cur.y), bf_hi(cur.y),
                       bf_lo(cur.z), bf_hi(cur.z), bf_lo(cur.w), bf_hi(cur.w)};
        bf16_t rr[8];
        #pragma unroll
        for (int j = 0; j < 8; j++) rr[j] = (bf16_t)(cf[j] + a[j] * inv);
        *(uint4*)(h2 + o) = *(uint4*)rr;
    }
}

// ---------------- final column mean over nodes (bf16 h2) ----------------
__global__ void colmean_kernel(const bf16_t* __restrict__ h2, float* __restrict__ out) {
    int t = threadIdx.x;
    int c2 = t & 63;
    int grp = t >> 6;
    float s0 = 0.f, s1 = 0.f;
    for (int n = blockIdx.x * 4 + grp; n < NNODES; n += gridDim.x * 4) {
        unsigned u = *((const unsigned*)(h2 + (size_t)n * 128) + c2);
        s0 += bf_lo(u);
        s1 += bf_hi(u);
    }
    __shared__ float red[256][2];
    red[t][0] = s0; red[t][1] = s1;
    __syncthreads();
    if (grp == 0) {
        float t0 = red[c2][0] + red[c2 + 64][0] + red[c2 + 128][0] + red[c2 + 192][0];
        float t1 = red[c2][1] + red[c2 + 64][1] + red[c2 + 128][1] + red[c2 + 192][1];
        atomicAdd(&out[2 * c2],     t0 * (1.0f / NNODES));
        atomicAdd(&out[2 * c2 + 1], t1 * (1.0f / NNODES));
    }
}

extern "C" void kernel_launch(void* const* d_in, const int* in_sizes, int n_in,
                              void* d_out, int out_size, void* d_ws, size_t ws_size,
                              hipStream_t stream) {
    const float* x  = (const float*)d_in[0];
    const int*   ei = (const int*)d_in[1];   // int32: [2, E]
    const int* src = ei;
    const int* dst = ei + NEDGES;

    const float* Wq1 = (const float*)d_in[2];  const float* bq1 = (const float*)d_in[3];
    const float* Wk1 = (const float*)d_in[4];  const float* bk1 = (const float*)d_in[5];
    const float* Wv1 = (const float*)d_in[6];  const float* bv1 = (const float*)d_in[7];
    const float* Ws1 = (const float*)d_in[8];  const float* bs1 = (const float*)d_in[9];
    const float* Wq2 = (const float*)d_in[10]; const float* bq2 = (const float*)d_in[11];
    const float* Wk2 = (const float*)d_in[12]; const float* bk2 = (const float*)d_in[13];
    const float* Wv2 = (const float*)d_in[14]; const float* bv2 = (const float*)d_in[15];
    const float* Ws2 = (const float*)d_in[16]; const float* bs2 = (const float*)d_in[17];

    float* out = (float*)d_out;

    // ---- workspace layout (byte offsets, 16B-aligned) ----
    char* ws = (char*)d_ws;
    bf16_t* q1    = (bf16_t*)(ws);                 // N*256 bf16  = 25,600,000
    u8*     kv1   = (u8*)(ws + 25600000);          // N*512 fp8   = 25,600,000
    u8*     hskip = (u8*)(ws + 51200000);          // N*256 fp8   = 12,800,000
    bf16_t* hbf   = (bf16_t*)(ws + 64000000);      // MPAD*256 bf16 = 25,624,576
    bf16_t* xbf   = (bf16_t*)(ws + 89624576);      // MPAD*128 bf16 = 12,812,288
    bf16_t* wt1   = (bf16_t*)(ws + 102436864);     // 262,144
    bf16_t* wt2   = (bf16_t*)(ws + 102699008);     // 262,144
    int* deg     = (int*)(ws + 102961152);         // N
    int* row_ptr = deg + NNODES;                   // N+1
    int* esrc    = row_ptr + NNODES + 1;           // E
    int* pack    = esrc + NEDGES;                  // E
    int* psum    = pack + NEDGES;                  // NBLK
    // layer-2 buffers alias dead layer-1 regions (stream-ordered lifetimes)
    bf16_t* q2  = (bf16_t*)(ws);                   // N*128 bf16 (over q1)
    u8*     kv2 = (u8*)(ws + 12800000);            // N*256 fp8  (over q1 tail)
    bf16_t* h2  = (bf16_t*)(ws + 25600000);        // N*128 bf16 (over kv1)

    hipMemsetAsync(deg, 0, sizeof(int) * NNODES, stream);
    hipMemsetAsync(out, 0, sizeof(float) * 128, stream);
    hipMemsetAsync(hbf + (size_t)NNODES * 256, 0, (size_t)(MPAD - NNODES) * 256 * sizeof(bf16_t), stream);

    // fused prep + count_deg (records per-dst ordinal in pack)
    W4 w1; w1.W[0] = Wq1; w1.W[1] = Wk1; w1.W[2] = Wv1; w1.W[3] = Ws1;
    W4 w2; w2.W[0] = Wq2; w2.W[1] = Wk2; w2.W[2] = Wv2; w2.W[3] = Ws2;
    prep_count_kernel<<<PREP_XBLK + PREP_WBLK + CNT_BLK, 256, 0, stream>>>(
        x, w1, w2, xbf, wt1, wt2, dst, deg, pack);

    // cooperative CSR: scan + scatter in one launch
    {
        void* cargs[] = {(void*)&deg, (void*)&psum, (void*)&row_ptr,
                         (void*)&src, (void*)&pack, (void*)&esrc};
        hipLaunchCooperativeKernel((void*)csr_coop_kernel, dim3(NBLK), dim3(256),
                                   cargs, 0, stream);
    }

    // layer 1 GEMM
    GemmOut a1;
    a1.bias[0] = bq1; a1.bias[1] = bk1; a1.bias[2] = bv1; a1.bias[3] = bs1;
    a1.out[0] = q1;   a1.out[1] = kv1;  a1.out[2] = kv1;  a1.out[3] = hskip;
    a1.mode[0] = 1;   a1.mode[1] = 2;   a1.mode[2] = 3;   a1.mode[3] = 6;
    a1.scale[0] = 0.125f; a1.scale[1] = 1.f; a1.scale[2] = 1.f; a1.scale[3] = 1.f;
    dim3 g1(MPAD / 128, 1024 / 128);   // 391 x 8
    gemm_mfma_kernel<128, 256><<<g1, 256, 0, stream>>>(xbf, wt1, a1);

    attn1_kernel<<<NNODES / 4, 256, 0, stream>>>(q1, kv1, hskip, row_ptr, esrc, hbf);

    // layer 2 GEMM
    GemmOut a2;
    a2.bias[0] = bq2; a2.bias[1] = bk2; a2.bias[2] = bv2; a2.bias[3] = bs2;
    a2.out[0] = q2;   a2.out[1] = kv2;  a2.out[2] = kv2;  a2.out[3] = h2;
    a2.mode[0] = 1;   a2.mode[1] = 4;   a2.mode[2] = 5;   a2.mode[3] = 1;
    a2.scale[0] = 0.08838834764831845f; a2.scale[1] = 1.f; a2.scale[2] = 1.f; a2.scale[3] = 1.f;
    dim3 g2(MPAD / 128, 512 / 128);    // 391 x 4
    gemm_mfma_kernel<256, 128><<<g2, 256, 0, stream>>>(hbf, wt2, a2);

    attn2_kernel<<<NNODES / 4, 256, 0, stream>>>(q2, kv2, row_ptr, esrc, h2);

    colmean_kernel<<<256, 256, 0, stream>>>(h2, out);
}

// Round 16
// 370.864 us; speedup vs baseline: 1.2634x; 1.2634x over previous
//
#include <hip/hip_runtime.h>
#include <math.h>

#define NNODES 50000
#define NEDGES 800000
#define MPAD   50048   // NNODES rounded up to 128
#define NBLK   196     // ceil(NNODES/256)
#define PREP_XBLK 6256 // MPAD*128/4/256
#define PREP_WBLK 1024 // (131072+131072)/256
#define CNT_BLK   3125 // NEDGES/256

typedef __bf16 bf16_t;
typedef unsigned char u8;
typedef __attribute__((ext_vector_type(8))) __bf16 bf16x8;
typedef __attribute__((ext_vector_type(4))) float  floatx4;
typedef __attribute__((ext_vector_type(2))) float  floatx2;

__device__ __forceinline__ float bf_lo(unsigned u) { return __uint_as_float(u << 16); }
__device__ __forceinline__ float bf_hi(unsigned u) { return __uint_as_float(u & 0xffff0000u); }

__device__ __forceinline__ void gload_lds16(const bf16_t* g, bf16_t* l) {
    __builtin_amdgcn_global_load_lds(
        (const __attribute__((address_space(1))) unsigned int*)g,
        (__attribute__((address_space(3))) unsigned int*)l, 16, 0, 0);
}

struct W4 { const float* W[4]; };

// ---- fused prep (vectorized x cast + weight transposes) + count_deg w/ ordinal ----
__global__ void prep_count_kernel(const float* __restrict__ x, W4 w1, W4 w2,
                                  bf16_t* __restrict__ xb, bf16_t* __restrict__ wt1,
                                  bf16_t* __restrict__ wt2,
                                  const int* __restrict__ dst, int* __restrict__ deg,
                                  int* __restrict__ pack) {
    int b = blockIdx.x;
    if (b < PREP_XBLK) {
        int i = (b * 256 + threadIdx.x) * 4;
        if (i < MPAD * 128) {
            int row = i >> 7;
            bf16_t r[4];
            if (row < NNODES) {
                float4 v = *(const float4*)(x + i);
                r[0] = (bf16_t)v.x; r[1] = (bf16_t)v.y;
                r[2] = (bf16_t)v.z; r[3] = (bf16_t)v.w;
            } else { r[0] = r[1] = r[2] = r[3] = (bf16_t)0.f; }
            *(uint2*)(xb + i) = *(uint2*)r;
        }
    } else if (b < PREP_XBLK + PREP_WBLK) {
        int j = (b - PREP_XBLK) * 256 + threadIdx.x;   // 0..262143
        if (j < 131072) {
            int c = j >> 7, k = j & 127;
            wt1[j] = (bf16_t)w1.W[c >> 8][(size_t)k * 256 + (c & 255)];
        } else {
            int jj = j - 131072;
            int c = jj >> 8, k = jj & 255;
            wt2[jj] = (bf16_t)w2.W[c >> 7][(size_t)k * 128 + (c & 127)];
        }
    } else {
        int e = (b - PREP_XBLK - PREP_WBLK) * 256 + threadIdx.x;
        if (e < NEDGES) {
            int d = dst[e];
            int ord = atomicAdd(&deg[d], 1);   // per-destination ordinal
            pack[e] = (ord << 16) | d;         // dst < 50000 < 2^16
        }
    }
}

// ---------------- CSR scan (separate kernels, full parallelism) ----------------
__global__ void blocksum_kernel(const int* __restrict__ deg, int* __restrict__ psum) {
    int t = threadIdx.x;
    int i = blockIdx.x * 256 + t;
    int v = (i < NNODES) ? deg[i] : 0;
    __shared__ int s[256];
    s[t] = v;
    __syncthreads();
    for (int off = 128; off; off >>= 1) {
        if (t < off) s[t] += s[t + off];
        __syncthreads();
    }
    if (t == 0) psum[blockIdx.x] = s[0];
}

__global__ void scanpart_kernel(int* __restrict__ psum) {
    __shared__ int s[256];
    int t = threadIdx.x;
    int v = (t < NBLK) ? psum[t] : 0;
    s[t] = v;
    __syncthreads();
    for (int off = 1; off < 256; off <<= 1) {
        int val = (t >= off) ? s[t - off] : 0;
        __syncthreads();
        s[t] += val;
        __syncthreads();
    }
    if (t < NBLK) psum[t] = s[t] - v;   // exclusive
}

__global__ void scanfinal_kernel(const int* __restrict__ deg, const int* __restrict__ psum,
                                 int* __restrict__ row_ptr) {
    int t = threadIdx.x;
    int b = blockIdx.x;
    int i = b * 256 + t;
    int v = (i < NNODES) ? deg[i] : 0;
    __shared__ int s[256];
    s[t] = v;
    __syncthreads();
    for (int off = 1; off < 256; off <<= 1) {
        int val = (t >= off) ? s[t - off] : 0;
        __syncthreads();
        s[t] += val;
        __syncthreads();
    }
    if (i <= NNODES) row_ptr[i] = psum[b] + s[t] - v;  // exclusive prefix
}

// atomic-free scatter: slot = row_ptr[dst] + ordinal
__global__ void scatter_kernel(const int* __restrict__ src, const int* __restrict__ pack,
                               const int* __restrict__ row_ptr, int* __restrict__ esrc) {
    int e = blockIdx.x * 256 + threadIdx.x;
    if (e >= NEDGES) return;
    int p = pack[e];
    int d = p & 0xFFFF;
    int ord = p >> 16;
    esrc[row_ptr[d] + ord] = src[e];
}

// ---------------- bf16 MFMA GEMM: C_mat = (A @ W_mat + b_mat) * scale ----------------
// modes: 1 = bf16 contiguous (applies scale), 6 = fp8 contiguous,
//        2/3 = fp8 kv1 k/v half (row 512B, 4B groups), 4/5 = fp8 kv2 k/v half (row 256B)
struct GemmOut {
    const float* bias[4];
    void*        out[4];
    int          mode[4];
    float        scale[4];
};

template <int K, int NC>
__global__ __launch_bounds__(256) void gemm_mfma_kernel(const bf16_t* __restrict__ A,
                                                        const bf16_t* __restrict__ Wt,
                                                        GemmOut args) {
    __shared__ __align__(16) char smem[36864];
    bf16_t* As = (bf16_t*)smem;            // [128][64] swizzled = 16 KB
    bf16_t* Bs = (bf16_t*)(smem + 16384);  // [128][64] swizzled = 16 KB

    int t    = threadIdx.x;
    int lane = t & 63;
    int w    = t >> 6;
    int wm   = w >> 1, wn = w & 1;
    int tile_r = blockIdx.x * 128;
    int tile_c = blockIdx.y * 128;
    int mat = tile_c / NC;
    int tcl = tile_c % NC;

    int rl = lane >> 3;            // local row 0..7 within an 8-row group
    int sc = (lane & 7) ^ rl;      // which data chunk this lane must fetch

    floatx4 acc[4][4] = {};

    for (int kk = 0; kk < K; kk += 64) {
        #pragma unroll
        for (int j = 0; j < 4; j++) {
            int q = w * 4 + j;     // 8-row group 0..15
            const bf16_t* ga = &A [(size_t)(tile_r + q * 8 + rl) * K + kk + sc * 8];
            const bf16_t* gb = &Wt[(size_t)(tile_c + q * 8 + rl) * K + kk + sc * 8];
            gload_lds16(ga, As + q * 512);
            gload_lds16(gb, Bs + q * 512);
        }
        __syncthreads();
        #pragma unroll
        for (int kh = 0; kh < 64; kh += 32) {
            int sw = (((kh >> 3) + (lane >> 4)) ^ (lane & 7)) << 3;  // swizzled chunk offset
            bf16x8 af[4], bfr[4];
            #pragma unroll
            for (int mi = 0; mi < 4; mi++)
                af[mi] = *(const bf16x8*)&As[(wm * 64 + mi * 16 + (lane & 15)) * 64 + sw];
            #pragma unroll
            for (int ni = 0; ni < 4; ni++)
                bfr[ni] = *(const bf16x8*)&Bs[(wn * 64 + ni * 16 + (lane & 15)) * 64 + sw];
            #pragma unroll
            for (int mi = 0; mi < 4; mi++)
                #pragma unroll
                for (int ni = 0; ni < 4; ni++)
                    acc[mi][ni] = __builtin_amdgcn_mfma_f32_16x16x32_bf16(af[mi], bfr[ni], acc[mi][ni], 0, 0, 0);
        }
        __syncthreads();
    }

    // ---- LDS-staged coalesced epilogue ----
    const float* bias = args.bias[mat];
    void* op   = args.out[mat];
    int   mode = args.mode[mat];
    float scl  = args.scale[mat];
    float bv[4];
    #pragma unroll
    for (int ni = 0; ni < 4; ni++) bv[ni] = bias[tcl + wn * 64 + ni * 16 + (lane & 15)];

    if (mode == 1) {
        bf16_t (*Ct)[136] = (bf16_t(*)[136])smem;
        #pragma unroll
        for (int mi = 0; mi < 4; mi++)
            #pragma unroll
            for (int r = 0; r < 4; r++) {
                int row = wm * 64 + mi * 16 + (lane >> 4) * 4 + r;
                #pragma unroll
                for (int ni = 0; ni < 4; ni++) {
                    int col = wn * 64 + ni * 16 + (lane & 15);
                    Ct[row][col] = (bf16_t)((acc[mi][ni][r] + bv[ni]) * scl);
                }
            }
        __syncthreads();
        bf16_t* o = (bf16_t*)op;
        #pragma unroll
        for (int it = 0; it < 8; it++) {
            int idx = t + it * 256;
            int row = idx >> 4;
            int cg  = idx & 15;
            int gr = tile_r + row;
            if (gr < NNODES)
                *(int4*)(o + (size_t)gr * NC + tcl + cg * 8) = *(int4*)&Ct[row][cg * 8];
        }
    } else {
        u8 (*Ct8)[136] = (u8(*)[136])smem;
        #pragma unroll
        for (int mi = 0; mi < 4; mi++)
            #pragma unroll
            for (int r = 0; r < 4; r++) {
                int row = wm * 64 + mi * 16 + (lane >> 4) * 4 + r;
                #pragma unroll
                for (int ni = 0; ni < 4; ni++) {
                    int col = wn * 64 + ni * 16 + (lane & 15);
                    float val = acc[mi][ni][r] + bv[ni];
                    Ct8[row][col] = (u8)(__builtin_amdgcn_cvt_pk_fp8_f32(val, val, 0, false) & 0xff);
                }
            }
        __syncthreads();
        u8* o = (u8*)op;
        if (mode == 6) {
            #pragma unroll
            for (int it = 0; it < 16; it++) {
                int idx = t + it * 256;
                int row = idx >> 5;
                int cg  = idx & 31;
                int gr = tile_r + row;
                if (gr < NNODES) {
                    unsigned v4 = *(unsigned*)&Ct8[row][cg * 4];
                    *(unsigned*)(o + (size_t)gr * NC + tcl + cg * 4) = v4;
                }
            }
        } else if (mode <= 3) {
            bool isK = (mode == 2);
            #pragma unroll
            for (int it = 0; it < 16; it++) {
                int idx = t + it * 256;
                int row = idx >> 5;
                int cg  = idx & 31;
                int gr = tile_r + row;
                if (gr < NNODES) {
                    unsigned v4 = *(unsigned*)&Ct8[row][cg * 4];
                    size_t a = (size_t)gr * 512 + (size_t)((tcl >> 2) + cg) * 8 + (isK ? 0 : 4);
                    *(unsigned*)(o + a) = v4;
                }
            }
        } else {
            bool isK = (mode == 4);
            #pragma unroll
            for (int it = 0; it < 32; it++) {
                int idx = t + it * 256;
                int row = idx >> 6;
                int g   = idx & 63;
                int gr = tile_r + row;
                if (gr < NNODES) {
                    unsigned short v2 = *(unsigned short*)&Ct8[row][g * 2];
                    size_t a = (size_t)gr * 256 + (size_t)((tcl >> 1) + g) * 4 + (isK ? 0 : 2);
                    *(unsigned short*)(o + a) = v2;
                }
            }
        }
    }
}

// ---- attention layer 1 (heads=4, d=64): ONE WAVE PER NODE, group-of-4 ring ----
__device__ __forceinline__ void attn1_step(uint2 kvv, bool valid,
                                           float q0, float q1, float q2, float q3,
                                           float& l, float& a0, float& a1, float& a2, float& a3) {
    floatx2 ka = __builtin_amdgcn_cvt_pk_f32_fp8((int)kvv.x, false);
    floatx2 kb = __builtin_amdgcn_cvt_pk_f32_fp8((int)kvv.x, true);
    float p = q0 * ka.x + q1 * ka.y + q2 * kb.x + q3 * kb.y;
    p += __shfl_xor(p, 1, 64);
    p += __shfl_xor(p, 2, 64);
    p += __shfl_xor(p, 4, 64);
    p += __shfl_xor(p, 8, 64);
    p = valid ? p : -INFINITY;
    float pe = __expf(p);
    floatx2 va = __builtin_amdgcn_cvt_pk_f32_fp8((int)kvv.y, false);
    floatx2 vb = __builtin_amdgcn_cvt_pk_f32_fp8((int)kvv.y, true);
    l  += pe;
    a0 += pe * va.x;
    a1 += pe * va.y;
    a2 += pe * vb.x;
    a3 += pe * vb.y;
}

__global__ void attn1_kernel(const bf16_t* __restrict__ q, const u8* __restrict__ kv,
                             const u8* __restrict__ skipf8,
                             const int* __restrict__ row_ptr, const int* __restrict__ esrc,
                             bf16_t* __restrict__ hout) {
    int n = blockIdx.x * 4 + (threadIdx.x >> 6);
    int lane = threadIdx.x & 63;
    int off = lane * 4;
    size_t lb = (size_t)(lane * 8);

    int beg = row_ptr[n], end = row_ptr[n + 1];

    uint2 qu = *(const uint2*)(q + (size_t)n * 256 + off);
    float q0 = bf_lo(qu.x), q1 = bf_hi(qu.x), q2 = bf_lo(qu.y), q3 = bf_hi(qu.y);

    float l = 0.f, a0 = 0.f, a1 = 0.f, a2 = 0.f, a3 = 0.f;

    if (beg < end) {
        int last = end - 1;
        int s0 = esrc[beg];
        int s1 = esrc[min(beg + 1, last)];
        int s2 = esrc[min(beg + 2, last)];
        int s3 = esrc[min(beg + 3, last)];
        uint2 k0 = *(const uint2*)(kv + (size_t)s0 * 512 + lb);
        uint2 k1 = *(const uint2*)(kv + (size_t)s1 * 512 + lb);
        uint2 k2 = *(const uint2*)(kv + (size_t)s2 * 512 + lb);
        uint2 k3 = *(const uint2*)(kv + (size_t)s3 * 512 + lb);

        for (int i = beg; i < end; i += 4) {
            int b = i + 4;
            int ns0 = esrc[min(b,     last)];
            int ns1 = esrc[min(b + 1, last)];
            int ns2 = esrc[min(b + 2, last)];
            int ns3 = esrc[min(b + 3, last)];

            attn1_step(k0, true,        q0, q1, q2, q3, l, a0, a1, a2, a3);
            k0 = *(const uint2*)(kv + (size_t)ns0 * 512 + lb);
            attn1_step(k1, i + 1 < end, q0, q1, q2, q3, l, a0, a1, a2, a3);
            k1 = *(const uint2*)(kv + (size_t)ns1 * 512 + lb);
            attn1_step(k2, i + 2 < end, q0, q1, q2, q3, l, a0, a1, a2, a3);
            k2 = *(const uint2*)(kv + (size_t)ns2 * 512 + lb);
            attn1_step(k3, i + 3 < end, q0, q1, q2, q3, l, a0, a1, a2, a3);
            k3 = *(const uint2*)(kv + (size_t)ns3 * 512 + lb);
        }
    }

    float inv = (l > 0.f) ? 1.f / l : 0.f;
    size_t o = (size_t)n * 256 + off;
    unsigned sk = *(const unsigned*)(skipf8 + o);
    floatx2 s01 = __builtin_amdgcn_cvt_pk_f32_fp8((int)sk, false);
    floatx2 s23 = __builtin_amdgcn_cvt_pk_f32_fp8((int)sk, true);
    bf16_t r[4];
    r[0] = (bf16_t)fmaxf(s01.x + a0 * inv, 0.f);
    r[1] = (bf16_t)fmaxf(s01.y + a1 * inv, 0.f);
    r[2] = (bf16_t)fmaxf(s23.x + a2 * inv, 0.f);
    r[3] = (bf16_t)fmaxf(s23.y + a3 * inv, 0.f);
    *(uint2*)(hout + o) = *(uint2*)r;
}

// ---- attention layer 2 (heads=1, d=128): ONE WAVE PER NODE, 4 edges/iter ----
__device__ __forceinline__ void attn2_step(uint4 kvv, bool valid, const float* qf,
                                           float& l, float* a) {
    floatx2 k01 = __builtin_amdgcn_cvt_pk_f32_fp8((int)kvv.x, false);
    floatx2 k23 = __builtin_amdgcn_cvt_pk_f32_fp8((int)kvv.y, false);
    floatx2 k45 = __builtin_amdgcn_cvt_pk_f32_fp8((int)kvv.z, false);
    floatx2 k67 = __builtin_amdgcn_cvt_pk_f32_fp8((int)kvv.w, false);
    float p = qf[0] * k01.x + qf[1] * k01.y + qf[2] * k23.x + qf[3] * k23.y
            + qf[4] * k45.x + qf[5] * k45.y + qf[6] * k67.x + qf[7] * k67.y;
    p += __shfl_xor(p, 1, 64);
    p += __shfl_xor(p, 2, 64);
    p += __shfl_xor(p, 4, 64);
    p += __shfl_xor(p, 8, 64);
    p = valid ? p : -INFINITY;
    float pe = __expf(p);
    floatx2 v01 = __builtin_amdgcn_cvt_pk_f32_fp8((int)kvv.x, true);
    floatx2 v23 = __builtin_amdgcn_cvt_pk_f32_fp8((int)kvv.y, true);
    floatx2 v45 = __builtin_amdgcn_cvt_pk_f32_fp8((int)kvv.z, true);
    floatx2 v67 = __builtin_amdgcn_cvt_pk_f32_fp8((int)kvv.w, true);
    l    += pe;
    a[0] += pe * v01.x;
    a[1] += pe * v01.y;
    a[2] += pe * v23.x;
    a[3] += pe * v23.y;
    a[4] += pe * v45.x;
    a[5] += pe * v45.y;
    a[6] += pe * v67.x;
    a[7] += pe * v67.y;
}

__global__ void attn2_kernel(const bf16_t* __restrict__ q, const u8* __restrict__ kv,
                             const int* __restrict__ row_ptr, const int* __restrict__ esrc,
                             bf16_t* __restrict__ h2) {
    int n = blockIdx.x * 4 + (threadIdx.x >> 6);
    int lane = threadIdx.x & 63;
    int quad = lane >> 4;
    int sub  = lane & 15;
    int d0 = sub * 8;
    size_t lb = (size_t)(sub * 16);

    int beg = row_ptr[n], end = row_ptr[n + 1];

    uint4 qu = *(const uint4*)(q + (size_t)n * 128 + d0);
    float qf[8] = {bf_lo(qu.x), bf_hi(qu.x), bf_lo(qu.y), bf_hi(qu.y),
                   bf_lo(qu.z), bf_hi(qu.z), bf_lo(qu.w), bf_hi(qu.w)};

    float l = 0.f, a[8] = {};

    if (beg < end) {
        int last = end - 1;
        int s0 = esrc[min(beg + quad,     last)];
        int s1 = esrc[min(beg + 4 + quad, last)];
        uint4 k0 = *(const uint4*)(kv + (size_t)s0 * 256 + lb);
        uint4 k1 = *(const uint4*)(kv + (size_t)s1 * 256 + lb);

        for (int i = beg; i < end; i += 4) {
            int ns = esrc[min(i + 8 + quad, last)];
            attn2_step(k0, i + quad < end, qf, l, a);
            k0 = k1;
            k1 = *(const uint4*)(kv + (size_t)ns * 256 + lb);
        }
    }

    l += __shfl_xor(l, 16, 64);
    l += __shfl_xor(l, 32, 64);
    #pragma unroll
    for (int j = 0; j < 8; j++) {
        a[j] += __shfl_xor(a[j], 16, 64);
        a[j] += __shfl_xor(a[j], 32, 64);
    }
    float inv = (l > 0.f) ? 1.f / l : 0.f;
    if (quad == 0) {
        size_t o = (size_t)n * 128 + d0;
        uint4 cur = *(const uint4*)(h2 + o);
        float cf[8] = {bf_lo(cur.x), bf_hi(cur.x), bf_lo(cur.y), bf_hi(cur.y),
                       bf_lo(cur.z), bf_hi(cur.z), bf_lo(cur.w), bf_hi(cur.w)};
        bf16_t rr[8];
        #pragma unroll
        for (int j = 0; j < 8; j++) rr[j] = (bf16_t)(cf[j] + a[j] * inv);
        *(uint4*)(h2 + o) = *(uint4*)rr;
    }
}

// ---------------- final column mean over nodes (bf16 h2) ----------------
__global__ void colmean_kernel(const bf16_t* __restrict__ h2, float* __restrict__ out) {
    int t = threadIdx.x;
    int c2 = t & 63;
    int grp = t >> 6;
    float s0 = 0.f, s1 = 0.f;
    for (int n = blockIdx.x * 4 + grp; n < NNODES; n += gridDim.x * 4) {
        unsigned u = *((const unsigned*)(h2 + (size_t)n * 128) + c2);
        s0 += bf_lo(u);
        s1 += bf_hi(u);
    }
    __shared__ float red[256][2];
    red[t][0] = s0; red[t][1] = s1;
    __syncthreads();
    if (grp == 0) {
        float t0 = red[c2][0] + red[c2 + 64][0] + red[c2 + 128][0] + red[c2 + 192][0];
        float t1 = red[c2][1] + red[c2 + 64][1] + red[c2 + 128][1] + red[c2 + 192][1];
        atomicAdd(&out[2 * c2],     t0 * (1.0f / NNODES));
        atomicAdd(&out[2 * c2 + 1], t1 * (1.0f / NNODES));
    }
}

extern "C" void kernel_launch(void* const* d_in, const int* in_sizes, int n_in,
                              void* d_out, int out_size, void* d_ws, size_t ws_size,
                              hipStream_t stream) {
    const float* x  = (const float*)d_in[0];
    const int*   ei = (const int*)d_in[1];   // int32: [2, E]
    const int* src = ei;
    const int* dst = ei + NEDGES;

    const float* Wq1 = (const float*)d_in[2];  const float* bq1 = (const float*)d_in[3];
    const float* Wk1 = (const float*)d_in[4];  const float* bk1 = (const float*)d_in[5];
    const float* Wv1 = (const float*)d_in[6];  const float* bv1 = (const float*)d_in[7];
    const float* Ws1 = (const float*)d_in[8];  const float* bs1 = (const float*)d_in[9];
    const float* Wq2 = (const float*)d_in[10]; const float* bq2 = (const float*)d_in[11];
    const float* Wk2 = (const float*)d_in[12]; const float* bk2 = (const float*)d_in[13];
    const float* Wv2 = (const float*)d_in[14]; const float* bv2 = (const float*)d_in[15];
    const float* Ws2 = (const float*)d_in[16]; const float* bs2 = (const float*)d_in[17];

    float* out = (float*)d_out;

    // ---- workspace layout (byte offsets, 16B-aligned) ----
    char* ws = (char*)d_ws;
    bf16_t* q1    = (bf16_t*)(ws);                 // N*256 bf16  = 25,600,000
    u8*     kv1   = (u8*)(ws + 25600000);          // N*512 fp8   = 25,600,000
    u8*     hskip = (u8*)(ws + 51200000);          // N*256 fp8   = 12,800,000
    bf16_t* hbf   = (bf16_t*)(ws + 64000000);      // MPAD*256 bf16 = 25,624,576
    bf16_t* xbf   = (bf16_t*)(ws + 89624576);      // MPAD*128 bf16 = 12,812,288
    bf16_t* wt1   = (bf16_t*)(ws + 102436864);     // 262,144
    bf16_t* wt2   = (bf16_t*)(ws + 102699008);     // 262,144
    int* deg     = (int*)(ws + 102961152);         // N
    int* row_ptr = deg + NNODES;                   // N+1
    int* esrc    = row_ptr + NNODES + 1;           // E
    int* pack    = esrc + NEDGES;                  // E
    int* psum    = pack + NEDGES;                  // NBLK
    // layer-2 buffers alias dead layer-1 regions (stream-ordered lifetimes)
    bf16_t* q2  = (bf16_t*)(ws);                   // N*128 bf16 (over q1)
    u8*     kv2 = (u8*)(ws + 12800000);            // N*256 fp8  (over q1 tail)
    bf16_t* h2  = (bf16_t*)(ws + 25600000);        // N*128 bf16 (over kv1)

    hipMemsetAsync(deg, 0, sizeof(int) * NNODES, stream);
    hipMemsetAsync(out, 0, sizeof(float) * 128, stream);
    hipMemsetAsync(hbf + (size_t)NNODES * 256, 0, (size_t)(MPAD - NNODES) * 256 * sizeof(bf16_t), stream);

    // fused prep + count_deg (records per-dst ordinal in pack)
    W4 w1; w1.W[0] = Wq1; w1.W[1] = Wk1; w1.W[2] = Wv1; w1.W[3] = Ws1;
    W4 w2; w2.W[0] = Wq2; w2.W[1] = Wk2; w2.W[2] = Wv2; w2.W[3] = Ws2;
    prep_count_kernel<<<PREP_XBLK + PREP_WBLK + CNT_BLK, 256, 0, stream>>>(
        x, w1, w2, xbf, wt1, wt2, dst, deg, pack);

    // CSR scan (separate kernels, full grid)
    blocksum_kernel<<<NBLK, 256, 0, stream>>>(deg, psum);
    scanpart_kernel<<<1, 256, 0, stream>>>(psum);
    scanfinal_kernel<<<NBLK, 256, 0, stream>>>(deg, psum, row_ptr);

    // atomic-free scatter (full grid)
    scatter_kernel<<<CNT_BLK, 256, 0, stream>>>(src, pack, row_ptr, esrc);

    // layer 1 GEMM
    GemmOut a1;
    a1.bias[0] = bq1; a1.bias[1] = bk1; a1.bias[2] = bv1; a1.bias[3] = bs1;
    a1.out[0] = q1;   a1.out[1] = kv1;  a1.out[2] = kv1;  a1.out[3] = hskip;
    a1.mode[0] = 1;   a1.mode[1] = 2;   a1.mode[2] = 3;   a1.mode[3] = 6;
    a1.scale[0] = 0.125f; a1.scale[1] = 1.f; a1.scale[2] = 1.f; a1.scale[3] = 1.f;
    dim3 g1(MPAD / 128, 1024 / 128);   // 391 x 8
    gemm_mfma_kernel<128, 256><<<g1, 256, 0, stream>>>(xbf, wt1, a1);

    attn1_kernel<<<NNODES / 4, 256, 0, stream>>>(q1, kv1, hskip, row_ptr, esrc, hbf);

    // layer 2 GEMM
    GemmOut a2;
    a2.bias[0] = bq2; a2.bias[1] = bk2; a2.bias[2] = bv2; a2.bias[3] = bs2;
    a2.out[0] = q2;   a2.out[1] = kv2;  a2.out[2] = kv2;  a2.out[3] = h2;
    a2.mode[0] = 1;   a2.mode[1] = 4;   a2.mode[2] = 5;   a2.mode[3] = 1;
    a2.scale[0] = 0.08838834764831845f; a2.scale[1] = 1.f; a2.scale[2] = 1.f; a2.scale[3] = 1.f;
    dim3 g2(MPAD / 128, 512 / 128);    // 391 x 4
    gemm_mfma_kernel<256, 128><<<g2, 256, 0, stream>>>(hbf, wt2, a2);

    attn2_kernel<<<NNODES / 4, 256, 0, stream>>>(q2, kv2, row_ptr, esrc, h2);

    colmean_kernel<<<256, 256, 0, stream>>>(h2, out);
}